// Round 8
// baseline (1953.592 us; speedup 1.0000x reference)
//
#include <hip/hip_runtime.h>
#include <hip/hip_bf16.h>
#include <cstdint>
#include <cstddef>

typedef __hip_bfloat16 bf16;
typedef short short8 __attribute__((ext_vector_type(8)));
typedef float f32x4 __attribute__((ext_vector_type(4)));

static inline int cdiv(int a, int b) { return (a + b - 1) / b; }

// DPP row-rotate add: pure-VALU 16-lane row sum (rotations 8,4,2,1 cover all
// offsets so every lane ends with the full sum).
template <int CTRL>
__device__ __forceinline__ float ror_add(float x)
{
    int t = __builtin_amdgcn_update_dpp(0, __builtin_bit_cast(int, x),
                                        CTRL, 0xf, 0xf, true);
    return x + __builtin_bit_cast(float, t);
}
__device__ __forceinline__ float row16_sum(float x)
{
    x = ror_add<0x128>(x);   // row_ror:8
    x = ror_add<0x124>(x);   // row_ror:4
    x = ror_add<0x122>(x);   // row_ror:2
    x = ror_add<0x121>(x);   // row_ror:1
    return x;
}

// ---------------------------------------------------------------------------
// fp32 -> bf16 conversion (n % 4 == 0)
// ---------------------------------------------------------------------------
__global__ __launch_bounds__(256) void cvt_k(
    const float* __restrict__ src, bf16* __restrict__ dst, int n)
{
    const int i = (blockIdx.x * 256 + threadIdx.x) * 4;
    if (i >= n) return;
    float4 v = *(const float4*)(src + i);
    bf16 o[4];
    o[0] = __float2bfloat16(v.x);
    o[1] = __float2bfloat16(v.y);
    o[2] = __float2bfloat16(v.z);
    o[3] = __float2bfloat16(v.w);
    *(int2*)(dst + i) = *(const int2*)o;
}

// ---------------------------------------------------------------------------
// 64-tile GEMM: C[M,N] = A[M,K] * W[N,K]^T
// MODE 1: f32 C (+bias if BIAS).  MODE 2: f32 C +=.
// MODE 4: f32 C + transposed cols>=32 copy into Cv2[(col-32)*4096+row].
// N arbitrary (predicated), K % 8 == 0, M % 64 == 0.
// ---------------------------------------------------------------------------
template <int MODE, bool BIAS>
__global__ __launch_bounds__(256) void gemm_bt(
    const bf16* __restrict__ A, const bf16* __restrict__ W,
    const float* __restrict__ bias, void* __restrict__ Cv,
    void* __restrict__ Cv2, int M, int N, int K)
{
    __shared__ short As[64 * 32];
    __shared__ short Ws[64 * 32];
    const int m0 = blockIdx.y * 64, n0 = blockIdx.x * 64;
    const int tid = threadIdx.x;
    const int wave = tid >> 6, lane = tid & 63;
    const int wm = wave >> 1, wn = wave & 1;
    const int lr = tid >> 2;
    const int lc = (tid & 3) * 8;
    const int i = lane & 15, q = lane >> 4;

    f32x4 acc[2][2];
    #pragma unroll
    for (int a = 0; a < 2; ++a)
        #pragma unroll
        for (int b = 0; b < 2; ++b) acc[a][b] = (f32x4){0.f, 0.f, 0.f, 0.f};

    const int nk = (K + 31) >> 5;
    for (int kt = 0; kt < nk; ++kt) {
        const int k0 = kt << 5;
        int4 av = {0, 0, 0, 0}, wv = {0, 0, 0, 0};
        if (k0 + lc < K) {
            av = *(const int4*)(A + (size_t)(m0 + lr) * K + k0 + lc);
            if (n0 + lr < N)
                wv = *(const int4*)(W + (size_t)(n0 + lr) * K + k0 + lc);
        }
        __syncthreads();
        *(int4*)&As[lr * 32 + lc] = av;
        *(int4*)&Ws[lr * 32 + lc] = wv;
        __syncthreads();
        short8 a0 = *(const short8*)&As[(wm * 32 + i) * 32 + q * 8];
        short8 a1 = *(const short8*)&As[(wm * 32 + 16 + i) * 32 + q * 8];
        short8 b0 = *(const short8*)&Ws[(wn * 32 + i) * 32 + q * 8];
        short8 b1 = *(const short8*)&Ws[(wn * 32 + 16 + i) * 32 + q * 8];
        acc[0][0] = __builtin_amdgcn_mfma_f32_16x16x32_bf16(a0, b0, acc[0][0], 0, 0, 0);
        acc[0][1] = __builtin_amdgcn_mfma_f32_16x16x32_bf16(a0, b1, acc[0][1], 0, 0, 0);
        acc[1][0] = __builtin_amdgcn_mfma_f32_16x16x32_bf16(a1, b0, acc[1][0], 0, 0, 0);
        acc[1][1] = __builtin_amdgcn_mfma_f32_16x16x32_bf16(a1, b1, acc[1][1], 0, 0, 0);
    }

    #pragma unroll
    for (int am = 0; am < 2; ++am) {
        #pragma unroll
        for (int an = 0; an < 2; ++an) {
            #pragma unroll
            for (int r = 0; r < 4; ++r) {
                const int row = m0 + wm * 32 + am * 16 + q * 4 + r;
                const int col = n0 + wn * 32 + an * 16 + i;
                if (col < N) {
                    float v = acc[am][an][r];
                    if (MODE == 1) {
                        if (BIAS) v += bias[col];
                        ((float*)Cv)[(size_t)row * N + col] = v;
                    } else if (MODE == 2) {
                        ((float*)Cv)[(size_t)row * N + col] += v;
                    } else {  // MODE 4
                        ((float*)Cv)[(size_t)row * N + col] = v;
                        if (col >= 32)
                            ((float*)Cv2)[(size_t)(col - 32) * 4096 + row] = v;
                    }
                }
            }
        }
    }
}

// ---------------------------------------------------------------------------
// 128x128-tile GEMM (m93-style), used where the grid is big enough (>=512
// blocks).  MODE 3: split bf16 (col<1024 -> Cv, else Cv2).
// ---------------------------------------------------------------------------
template <int MODE>
__global__ __launch_bounds__(256) void gemm128_bt(
    const bf16* __restrict__ A, const bf16* __restrict__ W,
    void* __restrict__ Cv, void* __restrict__ Cv2, int N, int K)
{
    __shared__ short As[128 * 32];
    __shared__ short Ws[128 * 32];
    const int m0 = blockIdx.y * 128, n0 = blockIdx.x * 128;
    const int tid = threadIdx.x;
    const int wave = tid >> 6, lane = tid & 63;
    const int wm = wave >> 1, wn = wave & 1;
    const int i = lane & 15, q = lane >> 4;
    const int r0 = tid >> 2;
    const int ko = (tid & 3) * 8;

    f32x4 acc[4][4];
    #pragma unroll
    for (int a = 0; a < 4; ++a)
        #pragma unroll
        for (int b = 0; b < 4; ++b) acc[a][b] = (f32x4){0.f, 0.f, 0.f, 0.f};

    const int nk = K >> 5;
    for (int kt = 0; kt < nk; ++kt) {
        const int k0 = kt << 5;
        const int4 a0 = *(const int4*)(A + (size_t)(m0 + r0) * K + k0 + ko);
        const int4 a1 = *(const int4*)(A + (size_t)(m0 + 64 + r0) * K + k0 + ko);
        const int4 w0 = *(const int4*)(W + (size_t)(n0 + r0) * K + k0 + ko);
        const int4 w1 = *(const int4*)(W + (size_t)(n0 + 64 + r0) * K + k0 + ko);
        __syncthreads();
        *(int4*)&As[r0 * 32 + ko] = a0;
        *(int4*)&As[(64 + r0) * 32 + ko] = a1;
        *(int4*)&Ws[r0 * 32 + ko] = w0;
        *(int4*)&Ws[(64 + r0) * 32 + ko] = w1;
        __syncthreads();
        short8 af[4], bfr[4];
        #pragma unroll
        for (int am = 0; am < 4; ++am)
            af[am] = *(const short8*)&As[(wm * 64 + am * 16 + i) * 32 + q * 8];
        #pragma unroll
        for (int an = 0; an < 4; ++an)
            bfr[an] = *(const short8*)&Ws[(wn * 64 + an * 16 + i) * 32 + q * 8];
        #pragma unroll
        for (int am = 0; am < 4; ++am)
            #pragma unroll
            for (int an = 0; an < 4; ++an)
                acc[am][an] = __builtin_amdgcn_mfma_f32_16x16x32_bf16(
                    af[am], bfr[an], acc[am][an], 0, 0, 0);
    }

    #pragma unroll
    for (int am = 0; am < 4; ++am) {
        #pragma unroll
        for (int an = 0; an < 4; ++an) {
            #pragma unroll
            for (int r = 0; r < 4; ++r) {
                const int row = m0 + wm * 64 + am * 16 + q * 4 + r;
                const int col = n0 + wn * 64 + an * 16 + i;
                const float v = acc[am][an][r];
                if (col < 1024)
                    ((bf16*)Cv)[(size_t)row * 1024 + col] = __float2bfloat16(v);
                else
                    ((bf16*)Cv2)[(size_t)row * 1024 + col - 1024] = __float2bfloat16(v);
            }
        }
    }
}

// ---------------------------------------------------------------------------
// RMSNorm over D=512
// ---------------------------------------------------------------------------
__global__ __launch_bounds__(256) void rmsnorm_k(
    const float* __restrict__ h, const float* __restrict__ w,
    bf16* __restrict__ out)
{
    const int row = blockIdx.x * 4 + (threadIdx.x >> 6);
    const int lane = threadIdx.x & 63;
    const float* hr = h + (size_t)row * 512;
    float v[8];
    float s = 0.f;
    #pragma unroll
    for (int j = 0; j < 8; ++j) {
        v[j] = hr[lane + j * 64];
        s += v[j] * v[j];
    }
    #pragma unroll
    for (int m = 32; m >= 1; m >>= 1) s += __shfl_xor(s, m, 64);
    const float scale = rsqrtf(s * (1.f / 512.f) + 1e-5f);
    #pragma unroll
    for (int j = 0; j < 8; ++j) {
        out[(size_t)row * 512 + lane + j * 64] =
            __float2bfloat16(v[j] * scale * w[lane + j * 64]);
    }
}

// ---------------------------------------------------------------------------
// Causal depthwise conv (K=4) + bias + SiLU.  input u_raw [t][1024]
// ---------------------------------------------------------------------------
__global__ __launch_bounds__(256) void conv_silu_k(
    const bf16* __restrict__ u_raw, const float* __restrict__ cw,
    const float* __restrict__ cb, bf16* __restrict__ uc)
{
    const int idx = blockIdx.x * 256 + threadIdx.x;   // t*1024 + d
    const int d = idx & 1023;
    const int t = idx >> 10;
    const int l = t & 1023;
    float acc = cb[d];
    #pragma unroll
    for (int j = 0; j < 4; ++j) {
        const int ls = l - 3 + j;
        if (ls >= 0)
            acc += cw[d * 4 + j] *
                   __bfloat162float(u_raw[(size_t)(t + j - 3) * 1024 + d]);
    }
    const float sg = acc / (1.f + __expf(-acc));      // silu
    uc[idx] = __float2bfloat16(sg);
}

// ---------------------------------------------------------------------------
// dt projection + softplus -> deltaT[d][t] (f32), duT[d][t] = delta*u (bf16)
// ---------------------------------------------------------------------------
__global__ __launch_bounds__(256) void dtproj_k(
    const float* __restrict__ xdbl, const bf16* __restrict__ uc,
    const float* __restrict__ dt_w, const float* __restrict__ dt_b,
    float* __restrict__ deltaT, bf16* __restrict__ duT)
{
    __shared__ float sd[16][32];
    const int m0 = blockIdx.x * 16;
    const int d = blockIdx.y * 256 + threadIdx.x;
    {
        const int f = threadIdx.x * 2;
        const int r = f >> 5, c = f & 31;
        float2 t = *(const float2*)(xdbl + (size_t)(m0 + r) * 64 + c);
        sd[r][c] = t.x;
        sd[r][c + 1] = t.y;
    }
    bf16 uv[16];
    #pragma unroll
    for (int m = 0; m < 16; ++m) uv[m] = uc[(size_t)(m0 + m) * 1024 + d];
    __syncthreads();
    float wf[32];
    #pragma unroll
    for (int r4 = 0; r4 < 8; ++r4) {
        float4 t = *(const float4*)(dt_w + (size_t)d * 32 + r4 * 4);
        wf[r4 * 4 + 0] = t.x;
        wf[r4 * 4 + 1] = t.y;
        wf[r4 * 4 + 2] = t.z;
        wf[r4 * 4 + 3] = t.w;
    }
    const float db = dt_b[d];
    float dlv[16];
    bf16 duv[16];
    #pragma unroll
    for (int m = 0; m < 16; ++m) {
        float acc = db;
        #pragma unroll
        for (int r = 0; r < 32; ++r) acc += sd[m][r] * wf[r];
        const float sp = (acc > 20.f) ? acc : log1pf(__expf(acc));
        dlv[m] = sp;
        duv[m] = __float2bfloat16(sp * __bfloat162float(uv[m]));
    }
    float* o1 = deltaT + (size_t)d * 4096 + m0;
    #pragma unroll
    for (int k = 0; k < 4; ++k) *(float4*)(o1 + k * 4) = *(float4*)(dlv + k * 4);
    bf16* o2 = duT + (size_t)d * 4096 + m0;
    *(int4*)(o2) = *(int4*)(duv);
    *(int4*)(o2 + 8) = *(int4*)(duv + 8);
}

// ---------------------------------------------------------------------------
// Chunked selective scan, pass 1 (zero-init per 128-step chunk).
// Chunk 0's y is final after this pass, so the u*Dp + silu(res) gate is
// applied here for c==0; other chunks write partial y (gated in scan2).
// ---------------------------------------------------------------------------
__global__ __launch_bounds__(256) void scan1_k(
    const float* __restrict__ deltaT, const bf16* __restrict__ duT,
    const float* __restrict__ bct, const float* __restrict__ A_log,
    const bf16* __restrict__ uc, const bf16* __restrict__ res,
    const float* __restrict__ Dp,
    bf16* __restrict__ y, float* __restrict__ S_end, float* __restrict__ P_end)
{
    const int c = blockIdx.y, b = blockIdx.z;
    const int dl = threadIdx.x >> 4, n = threadIdx.x & 15;
    const int d = blockIdx.x * 16 + dl;
    const float A = -__expf(A_log[d * 16 + n]);
    const float Dpv = Dp[d];
    float h = 0.f, P = 1.f;
    const int base = b * 1024 + c * 128;
    const float* dp = deltaT + (size_t)d * 4096 + base;
    const bf16*  sp = duT + (size_t)d * 4096 + base;
    const float* Bp = bct + (size_t)n * 4096 + base;
    const float* Cp = bct + (size_t)(16 + n) * 4096 + base;
    const bf16* up = uc + (size_t)base * 1024 + d;
    const bf16* rp = res + (size_t)base * 1024 + d;
    bf16* yp = y + (size_t)base * 1024 + d;

    for (int g = 0; g < 16; ++g) {
        const int o = g * 8;
        const f32x4 dva = *(const f32x4*)(dp + o);
        const f32x4 dvb = *(const f32x4*)(dp + o + 4);
        const int4  svv = *(const int4*)(sp + o);
        const f32x4 Bva = *(const f32x4*)(Bp + o);
        const f32x4 Bvb = *(const f32x4*)(Bp + o + 4);
        const f32x4 Cva = *(const f32x4*)(Cp + o);
        const f32x4 Cvb = *(const f32x4*)(Cp + o + 4);
        bf16 su[8];
        *(int4*)su = svv;
        float e[8], s[8], Cw[8];
        #pragma unroll
        for (int j = 0; j < 4; ++j) {
            e[j]     = __expf(A * dva[j]);
            e[4 + j] = __expf(A * dvb[j]);
            s[j]     = __bfloat162float(su[j]) * Bva[j];
            s[4 + j] = __bfloat162float(su[4 + j]) * Bvb[j];
            Cw[j]     = Cva[j];
            Cw[4 + j] = Cvb[j];
        }
        #pragma unroll
        for (int j = 0; j < 8; ++j) {
            h = e[j] * h + s[j];
            P *= e[j];
            const float cc = row16_sum(h * Cw[j]);
            if (n == 0) {
                const size_t ti = (size_t)(o + j) * 1024;
                if (c == 0) {
                    const float u = __bfloat162float(up[ti]);
                    const float r = __bfloat162float(rp[ti]);
                    const float gate = r / (1.f + __expf(-r));
                    yp[ti] = __float2bfloat16((cc + u * Dpv) * gate);
                } else {
                    yp[ti] = __float2bfloat16(cc);
                }
            }
        }
    }
    const size_t so = ((size_t)(b * 8 + c) * 1024 + d) * 16 + n;
    S_end[so] = h;
    P_end[so] = P;
}

// ---------------------------------------------------------------------------
// Chunk-boundary fix: per (b,d,n), sequentially combine 8 chunks.
// ---------------------------------------------------------------------------
__global__ __launch_bounds__(256) void fix_k(
    float* __restrict__ S_end, const float* __restrict__ P_end)
{
    const int idx = blockIdx.x * 256 + threadIdx.x;
    const int b = idx >> 14, rem = idx & 16383;
    float* Sb = S_end + (size_t)b * 8 * 16384 + rem;
    const float* Pb = P_end + (size_t)b * 8 * 16384 + rem;
    float h0 = 0.f;
    #pragma unroll
    for (int c = 1; c < 8; ++c) {
        const float s = Sb[(size_t)(c - 1) * 16384];
        const float p = Pb[(size_t)(c - 1) * 16384];
        h0 = s + p * h0;
        Sb[(size_t)(c - 1) * 16384] = h0;
    }
}

// ---------------------------------------------------------------------------
// Chunked scan pass 2 (chunks 1..7): y = (y_partial + C.(P_t*h0) + u*Dp)
//                                         * silu(res)     [gate fused]
// ---------------------------------------------------------------------------
__global__ __launch_bounds__(256) void scan2_k(
    const float* __restrict__ deltaT, const float* __restrict__ bct,
    const float* __restrict__ A_log, const float* __restrict__ h0buf,
    const bf16* __restrict__ uc, const bf16* __restrict__ res,
    const float* __restrict__ Dp, bf16* __restrict__ y)
{
    const int c = blockIdx.y + 1;
    const int b = blockIdx.z;
    const int dl = threadIdx.x >> 4, n = threadIdx.x & 15;
    const int d = blockIdx.x * 16 + dl;
    const float A = -__expf(A_log[d * 16 + n]);
    const float Dpv = Dp[d];
    float q = h0buf[((size_t)(b * 8 + c - 1) * 1024 + d) * 16 + n];
    const int base = b * 1024 + c * 128;
    const float* dp = deltaT + (size_t)d * 4096 + base;
    const float* Cp = bct + (size_t)(16 + n) * 4096 + base;
    const bf16* up = uc + (size_t)base * 1024 + d;
    const bf16* rp = res + (size_t)base * 1024 + d;
    bf16* yp = y + (size_t)base * 1024 + d;

    for (int g = 0; g < 16; ++g) {
        const int o = g * 8;
        const f32x4 dva = *(const f32x4*)(dp + o);
        const f32x4 dvb = *(const f32x4*)(dp + o + 4);
        const f32x4 Cva = *(const f32x4*)(Cp + o);
        const f32x4 Cvb = *(const f32x4*)(Cp + o + 4);
        float e[8], Cw[8];
        #pragma unroll
        for (int j = 0; j < 4; ++j) {
            e[j]     = __expf(A * dva[j]);
            e[4 + j] = __expf(A * dvb[j]);
            Cw[j]     = Cva[j];
            Cw[4 + j] = Cvb[j];
        }
        #pragma unroll
        for (int j = 0; j < 8; ++j) {
            q *= e[j];
            const float cc = row16_sum(q * Cw[j]);
            if (n == 0) {
                const size_t ti = (size_t)(o + j) * 1024;
                const float yold = __bfloat162float(yp[ti]);
                const float u = __bfloat162float(up[ti]);
                const float r = __bfloat162float(rp[ti]);
                const float gate = r / (1.f + __expf(-r));
                yp[ti] = __float2bfloat16((yold + cc + u * Dpv) * gate);
            }
        }
    }
}

// ---------------------------------------------------------------------------
extern "C" void kernel_launch(void* const* d_in, const int* in_sizes, int n_in,
                              void* d_out, int out_size, void* d_ws, size_t ws_size,
                              hipStream_t stream)
{
    const float* x         = (const float*)d_in[0];
    const float* in_w      = (const float*)d_in[1];
    const float* in_b      = (const float*)d_in[2];
    const float* norm_w    = (const float*)d_in[3];
    const float* inproj_w  = (const float*)d_in[4];
    const float* conv_w    = (const float*)d_in[5];
    const float* conv_b    = (const float*)d_in[6];
    const float* xproj_w   = (const float*)d_in[7];
    const float* dt_w      = (const float*)d_in[8];
    const float* dt_b      = (const float*)d_in[9];
    const float* A_log     = (const float*)d_in[10];
    const float* Dp        = (const float*)d_in[11];
    const float* outproj_w = (const float*)d_in[12];
    const float* normf_w   = (const float*)d_in[13];
    const float* out_w     = (const float*)d_in[14];
    float* out = (float*)d_out;

    char* ws = (char*)d_ws;
    float* h      = (float*)(ws);               //  8388608 B
    bf16*  hn     = (bf16*)(ws + 8388608);      //  4194304 (scan phase: S/P overlay)
    float* S_end  = (float*)(ws + 8388608);     //  2097152 (overlay on hn)
    float* P_end  = (float*)(ws + 10485760);    //  2097152 (overlay on hn)
    bf16*  u_raw  = (bf16*)(ws + 12582912);     //  8388608 (later reused as duT)
    bf16*  res    = (bf16*)(ws + 20971520);     //  8388608
    bf16*  uc     = (bf16*)(ws + 29360128);     //  8388608
    float* xdbl   = (float*)(ws + 37748736);    //  1048576
    float* deltaT = (float*)(ws + 38797312);    // 16777216
    bf16*  yb     = (bf16*)(ws + 55574528);     //  8388608
    bf16*  xb     = (bf16*)(ws + 63963136);     //   655360 (dead after 1st GEMM)
    float* bct    = (float*)(ws + 63963136);    //   524288 (reuses xb region)
    bf16*  w_in   = (bf16*)(ws + 64618496);     //    81920
    bf16*  w_inp  = (bf16*)(ws + 64700416);     // 12582912
    bf16*  w_xp   = (bf16*)(ws + 77283328);     //   786432
    bf16*  w_outp = (bf16*)(ws + 78069760);     //  6291456
    bf16*  w_out  = (bf16*)(ws + 84361216);     //    81920
    bf16*  duT    = u_raw;                      // overlay: u_raw dead after conv

    const int M = 4096;  // B*L tokens

    cvt_k<<<cdiv(4096 * 80, 1024), 256, 0, stream>>>(x, xb, 4096 * 80);
    cvt_k<<<cdiv(512 * 80, 1024), 256, 0, stream>>>(in_w, w_in, 512 * 80);
    cvt_k<<<cdiv(6 * 2048 * 512, 1024), 256, 0, stream>>>(inproj_w, w_inp, 6 * 2048 * 512);
    cvt_k<<<cdiv(6 * 64 * 1024, 1024), 256, 0, stream>>>(xproj_w, w_xp, 6 * 64 * 1024);
    cvt_k<<<cdiv(6 * 512 * 1024, 1024), 256, 0, stream>>>(outproj_w, w_outp, 6 * 512 * 1024);
    cvt_k<<<cdiv(80 * 512, 1024), 256, 0, stream>>>(out_w, w_out, 80 * 512);

    // input projection: h = x @ in_w^T + in_b   [4096,512] K=80
    gemm_bt<1, true><<<dim3(512 / 64, M / 64), 256, 0, stream>>>(
        xb, w_in, in_b, h, nullptr, M, 512, 80);

    for (int i = 0; i < 6; ++i) {
        rmsnorm_k<<<M / 4, 256, 0, stream>>>(h, norm_w + (size_t)i * 512, hn);
        // split projection: u_raw | res = hn @ inproj_w^T   [4096,2048] K=512
        gemm128_bt<3><<<dim3(2048 / 128, M / 128), 256, 0, stream>>>(
            hn, w_inp + (size_t)i * 2048 * 512, u_raw, res, 2048, 512);
        conv_silu_k<<<(M * 1024) / 256, 256, 0, stream>>>(
            u_raw, conv_w + (size_t)i * 1024 * 4, conv_b + (size_t)i * 1024, uc);
        // xdbl = uc @ xproj_w^T  [4096,64] K=1024, + B/C transposed into bct
        gemm_bt<4, false><<<dim3(1, M / 64), 256, 0, stream>>>(
            uc, w_xp + (size_t)i * 64 * 1024, nullptr, xdbl, bct, M, 64, 1024);
        dtproj_k<<<dim3(M / 16, 4), 256, 0, stream>>>(
            xdbl, uc, dt_w + (size_t)i * 1024 * 32, dt_b + (size_t)i * 1024,
            deltaT, duT);
        scan1_k<<<dim3(64, 8, 4), 256, 0, stream>>>(
            deltaT, duT, bct, A_log + (size_t)i * 1024 * 16,
            uc, res, Dp + (size_t)i * 1024, yb, S_end, P_end);
        fix_k<<<65536 / 256, 256, 0, stream>>>(S_end, P_end);
        scan2_k<<<dim3(64, 7, 4), 256, 0, stream>>>(
            deltaT, bct, A_log + (size_t)i * 1024 * 16, S_end,
            uc, res, Dp + (size_t)i * 1024, yb);
        // h += yb @ outproj_w^T  [4096,512] K=1024  (64-tile: 512-block grid)
        gemm_bt<2, false><<<dim3(512 / 64, M / 64), 256, 0, stream>>>(
            yb, w_outp + (size_t)i * 512 * 1024, nullptr, h, nullptr, M, 512, 1024);
    }

    rmsnorm_k<<<M / 4, 256, 0, stream>>>(h, normf_w, hn);
    // out = hn @ out_w^T   [4096,80] K=512  (fp32 output)
    gemm_bt<1, false><<<dim3(cdiv(80, 64), M / 64), 256, 0, stream>>>(
        hn, w_out, nullptr, out, nullptr, M, 80, 512);
}

// Round 9
// 1718.234 us; speedup vs baseline: 1.1370x; 1.1370x over previous
//
#include <hip/hip_runtime.h>
#include <hip/hip_bf16.h>
#include <cstdint>
#include <cstddef>

typedef __hip_bfloat16 bf16;
typedef short short8 __attribute__((ext_vector_type(8)));
typedef float f32x4 __attribute__((ext_vector_type(4)));

static inline int cdiv(int a, int b) { return (a + b - 1) / b; }

// DPP row-rotate add: pure-VALU 16-lane row sum (rotations 8,4,2,1 cover all
// offsets so every lane ends with the full sum).
template <int CTRL>
__device__ __forceinline__ float ror_add(float x)
{
    int t = __builtin_amdgcn_update_dpp(0, __builtin_bit_cast(int, x),
                                        CTRL, 0xf, 0xf, true);
    return x + __builtin_bit_cast(float, t);
}
__device__ __forceinline__ float row16_sum(float x)
{
    x = ror_add<0x128>(x);   // row_ror:8
    x = ror_add<0x124>(x);   // row_ror:4
    x = ror_add<0x122>(x);   // row_ror:2
    x = ror_add<0x121>(x);   // row_ror:1
    return x;
}

// ---------------------------------------------------------------------------
// fp32 -> bf16 conversion (n % 4 == 0)
// ---------------------------------------------------------------------------
__global__ __launch_bounds__(256) void cvt_k(
    const float* __restrict__ src, bf16* __restrict__ dst, int n)
{
    const int i = (blockIdx.x * 256 + threadIdx.x) * 4;
    if (i >= n) return;
    float4 v = *(const float4*)(src + i);
    bf16 o[4];
    o[0] = __float2bfloat16(v.x);
    o[1] = __float2bfloat16(v.y);
    o[2] = __float2bfloat16(v.z);
    o[3] = __float2bfloat16(v.w);
    *(int2*)(dst + i) = *(const int2*)o;
}

// ---------------------------------------------------------------------------
// 64-tile GEMM: C[M,N] = A[M,K] * W[N,K]^T
// MODE 1: f32 C (+bias if BIAS).  MODE 2: f32 C +=.
// MODE 4: f32 C + transposed cols>=32 copy into Cv2[(col-32)*4096+row].
// N arbitrary (predicated), K % 8 == 0, M % 64 == 0.
// Used for small-N / odd shapes where the 128-tile grid would be <512 blocks.
// ---------------------------------------------------------------------------
template <int MODE, bool BIAS>
__global__ __launch_bounds__(256) void gemm_bt(
    const bf16* __restrict__ A, const bf16* __restrict__ W,
    const float* __restrict__ bias, void* __restrict__ Cv,
    void* __restrict__ Cv2, int M, int N, int K)
{
    __shared__ short As[64 * 32];
    __shared__ short Ws[64 * 32];
    const int m0 = blockIdx.y * 64, n0 = blockIdx.x * 64;
    const int tid = threadIdx.x;
    const int wave = tid >> 6, lane = tid & 63;
    const int wm = wave >> 1, wn = wave & 1;
    const int lr = tid >> 2;
    const int lc = (tid & 3) * 8;
    const int i = lane & 15, q = lane >> 4;

    f32x4 acc[2][2];
    #pragma unroll
    for (int a = 0; a < 2; ++a)
        #pragma unroll
        for (int b = 0; b < 2; ++b) acc[a][b] = (f32x4){0.f, 0.f, 0.f, 0.f};

    const int nk = (K + 31) >> 5;
    for (int kt = 0; kt < nk; ++kt) {
        const int k0 = kt << 5;
        int4 av = {0, 0, 0, 0}, wv = {0, 0, 0, 0};
        if (k0 + lc < K) {
            av = *(const int4*)(A + (size_t)(m0 + lr) * K + k0 + lc);
            if (n0 + lr < N)
                wv = *(const int4*)(W + (size_t)(n0 + lr) * K + k0 + lc);
        }
        __syncthreads();
        *(int4*)&As[lr * 32 + lc] = av;
        *(int4*)&Ws[lr * 32 + lc] = wv;
        __syncthreads();
        short8 a0 = *(const short8*)&As[(wm * 32 + i) * 32 + q * 8];
        short8 a1 = *(const short8*)&As[(wm * 32 + 16 + i) * 32 + q * 8];
        short8 b0 = *(const short8*)&Ws[(wn * 32 + i) * 32 + q * 8];
        short8 b1 = *(const short8*)&Ws[(wn * 32 + 16 + i) * 32 + q * 8];
        acc[0][0] = __builtin_amdgcn_mfma_f32_16x16x32_bf16(a0, b0, acc[0][0], 0, 0, 0);
        acc[0][1] = __builtin_amdgcn_mfma_f32_16x16x32_bf16(a0, b1, acc[0][1], 0, 0, 0);
        acc[1][0] = __builtin_amdgcn_mfma_f32_16x16x32_bf16(a1, b0, acc[1][0], 0, 0, 0);
        acc[1][1] = __builtin_amdgcn_mfma_f32_16x16x32_bf16(a1, b1, acc[1][1], 0, 0, 0);
    }

    #pragma unroll
    for (int am = 0; am < 2; ++am) {
        #pragma unroll
        for (int an = 0; an < 2; ++an) {
            #pragma unroll
            for (int r = 0; r < 4; ++r) {
                const int row = m0 + wm * 32 + am * 16 + q * 4 + r;
                const int col = n0 + wn * 32 + an * 16 + i;
                if (col < N) {
                    float v = acc[am][an][r];
                    if (MODE == 1) {
                        if (BIAS) v += bias[col];
                        ((float*)Cv)[(size_t)row * N + col] = v;
                    } else if (MODE == 2) {
                        ((float*)Cv)[(size_t)row * N + col] += v;
                    } else {  // MODE 4
                        ((float*)Cv)[(size_t)row * N + col] = v;
                        if (col >= 32)
                            ((float*)Cv2)[(size_t)(col - 32) * 4096 + row] = v;
                    }
                }
            }
        }
    }
}

// ---------------------------------------------------------------------------
// 128x128-tile GEMM (m93-style) — only for grids >= 512 blocks (inproj).
// MODE 3: split bf16 write (col<1024 -> Cv, else Cv2).
// ---------------------------------------------------------------------------
template <int MODE>
__global__ __launch_bounds__(256) void gemm128_bt(
    const bf16* __restrict__ A, const bf16* __restrict__ W,
    void* __restrict__ Cv, void* __restrict__ Cv2, int N, int K)
{
    __shared__ short As[128 * 32];
    __shared__ short Ws[128 * 32];
    const int m0 = blockIdx.y * 128, n0 = blockIdx.x * 128;
    const int tid = threadIdx.x;
    const int wave = tid >> 6, lane = tid & 63;
    const int wm = wave >> 1, wn = wave & 1;
    const int i = lane & 15, q = lane >> 4;
    const int r0 = tid >> 2;
    const int ko = (tid & 3) * 8;

    f32x4 acc[4][4];
    #pragma unroll
    for (int a = 0; a < 4; ++a)
        #pragma unroll
        for (int b = 0; b < 4; ++b) acc[a][b] = (f32x4){0.f, 0.f, 0.f, 0.f};

    const int nk = K >> 5;
    for (int kt = 0; kt < nk; ++kt) {
        const int k0 = kt << 5;
        const int4 a0 = *(const int4*)(A + (size_t)(m0 + r0) * K + k0 + ko);
        const int4 a1 = *(const int4*)(A + (size_t)(m0 + 64 + r0) * K + k0 + ko);
        const int4 w0 = *(const int4*)(W + (size_t)(n0 + r0) * K + k0 + ko);
        const int4 w1 = *(const int4*)(W + (size_t)(n0 + 64 + r0) * K + k0 + ko);
        __syncthreads();
        *(int4*)&As[r0 * 32 + ko] = a0;
        *(int4*)&As[(64 + r0) * 32 + ko] = a1;
        *(int4*)&Ws[r0 * 32 + ko] = w0;
        *(int4*)&Ws[(64 + r0) * 32 + ko] = w1;
        __syncthreads();
        short8 af[4], bfr[4];
        #pragma unroll
        for (int am = 0; am < 4; ++am)
            af[am] = *(const short8*)&As[(wm * 64 + am * 16 + i) * 32 + q * 8];
        #pragma unroll
        for (int an = 0; an < 4; ++an)
            bfr[an] = *(const short8*)&Ws[(wn * 64 + an * 16 + i) * 32 + q * 8];
        #pragma unroll
        for (int am = 0; am < 4; ++am)
            #pragma unroll
            for (int an = 0; an < 4; ++an)
                acc[am][an] = __builtin_amdgcn_mfma_f32_16x16x32_bf16(
                    af[am], bfr[an], acc[am][an], 0, 0, 0);
    }

    #pragma unroll
    for (int am = 0; am < 4; ++am) {
        #pragma unroll
        for (int an = 0; an < 4; ++an) {
            #pragma unroll
            for (int r = 0; r < 4; ++r) {
                const int row = m0 + wm * 64 + am * 16 + q * 4 + r;
                const int col = n0 + wn * 64 + an * 16 + i;
                const float v = acc[am][an][r];
                if (col < 1024)
                    ((bf16*)Cv)[(size_t)row * 1024 + col] = __float2bfloat16(v);
                else
                    ((bf16*)Cv2)[(size_t)row * 1024 + col - 1024] = __float2bfloat16(v);
            }
        }
    }
}

// ---------------------------------------------------------------------------
// RMSNorm over D=512
// ---------------------------------------------------------------------------
__global__ __launch_bounds__(256) void rmsnorm_k(
    const float* __restrict__ h, const float* __restrict__ w,
    bf16* __restrict__ out)
{
    const int row = blockIdx.x * 4 + (threadIdx.x >> 6);
    const int lane = threadIdx.x & 63;
    const float* hr = h + (size_t)row * 512;
    float v[8];
    float s = 0.f;
    #pragma unroll
    for (int j = 0; j < 8; ++j) {
        v[j] = hr[lane + j * 64];
        s += v[j] * v[j];
    }
    #pragma unroll
    for (int m = 32; m >= 1; m >>= 1) s += __shfl_xor(s, m, 64);
    const float scale = rsqrtf(s * (1.f / 512.f) + 1e-5f);
    #pragma unroll
    for (int j = 0; j < 8; ++j) {
        out[(size_t)row * 512 + lane + j * 64] =
            __float2bfloat16(v[j] * scale * w[lane + j * 64]);
    }
}

// ---------------------------------------------------------------------------
// Causal depthwise conv (K=4) + bias + SiLU.  input u_raw [t][1024]
// ---------------------------------------------------------------------------
__global__ __launch_bounds__(256) void conv_silu_k(
    const bf16* __restrict__ u_raw, const float* __restrict__ cw,
    const float* __restrict__ cb, bf16* __restrict__ uc)
{
    const int idx = blockIdx.x * 256 + threadIdx.x;   // t*1024 + d
    const int d = idx & 1023;
    const int t = idx >> 10;
    const int l = t & 1023;
    float acc = cb[d];
    #pragma unroll
    for (int j = 0; j < 4; ++j) {
        const int ls = l - 3 + j;
        if (ls >= 0)
            acc += cw[d * 4 + j] *
                   __bfloat162float(u_raw[(size_t)(t + j - 3) * 1024 + d]);
    }
    const float sg = acc / (1.f + __expf(-acc));      // silu
    uc[idx] = __float2bfloat16(sg);
}

// ---------------------------------------------------------------------------
// dt projection + softplus -> deltaT[d][t] (f32), duT[d][t] = delta*u (bf16)
// ---------------------------------------------------------------------------
__global__ __launch_bounds__(256) void dtproj_k(
    const float* __restrict__ xdbl, const bf16* __restrict__ uc,
    const float* __restrict__ dt_w, const float* __restrict__ dt_b,
    float* __restrict__ deltaT, bf16* __restrict__ duT)
{
    __shared__ float sd[16][32];
    const int m0 = blockIdx.x * 16;
    const int d = blockIdx.y * 256 + threadIdx.x;
    {
        const int f = threadIdx.x * 2;
        const int r = f >> 5, c = f & 31;
        float2 t = *(const float2*)(xdbl + (size_t)(m0 + r) * 64 + c);
        sd[r][c] = t.x;
        sd[r][c + 1] = t.y;
    }
    bf16 uv[16];
    #pragma unroll
    for (int m = 0; m < 16; ++m) uv[m] = uc[(size_t)(m0 + m) * 1024 + d];
    __syncthreads();
    float wf[32];
    #pragma unroll
    for (int r4 = 0; r4 < 8; ++r4) {
        float4 t = *(const float4*)(dt_w + (size_t)d * 32 + r4 * 4);
        wf[r4 * 4 + 0] = t.x;
        wf[r4 * 4 + 1] = t.y;
        wf[r4 * 4 + 2] = t.z;
        wf[r4 * 4 + 3] = t.w;
    }
    const float db = dt_b[d];
    float dlv[16];
    bf16 duv[16];
    #pragma unroll
    for (int m = 0; m < 16; ++m) {
        float acc = db;
        #pragma unroll
        for (int r = 0; r < 32; ++r) acc += sd[m][r] * wf[r];
        const float sp = (acc > 20.f) ? acc : log1pf(__expf(acc));
        dlv[m] = sp;
        duv[m] = __float2bfloat16(sp * __bfloat162float(uv[m]));
    }
    float* o1 = deltaT + (size_t)d * 4096 + m0;
    #pragma unroll
    for (int k = 0; k < 4; ++k) *(float4*)(o1 + k * 4) = *(float4*)(dlv + k * 4);
    bf16* o2 = duT + (size_t)d * 4096 + m0;
    *(int4*)(o2) = *(int4*)(duv);
    *(int4*)(o2 + 8) = *(int4*)(duv + 8);
}

// ---------------------------------------------------------------------------
// Chunked selective scan, pass 1 (zero-init per 128-step chunk).
// NOTE: keep the n==0 store path load-free — adding loads here cost 36% (R8).
// ---------------------------------------------------------------------------
__global__ __launch_bounds__(256) void scan1_k(
    const float* __restrict__ deltaT, const bf16* __restrict__ duT,
    const float* __restrict__ bct, const float* __restrict__ A_log,
    bf16* __restrict__ y, float* __restrict__ S_end, float* __restrict__ P_end)
{
    const int c = blockIdx.y, b = blockIdx.z;
    const int dl = threadIdx.x >> 4, n = threadIdx.x & 15;
    const int d = blockIdx.x * 16 + dl;
    const float A = -__expf(A_log[d * 16 + n]);
    float h = 0.f, P = 1.f;
    const int base = b * 1024 + c * 128;
    const float* dp = deltaT + (size_t)d * 4096 + base;
    const bf16*  sp = duT + (size_t)d * 4096 + base;
    const float* Bp = bct + (size_t)n * 4096 + base;
    const float* Cp = bct + (size_t)(16 + n) * 4096 + base;
    bf16* yp = y + (size_t)base * 1024 + d;

    for (int g = 0; g < 16; ++g) {
        const int o = g * 8;
        const f32x4 dva = *(const f32x4*)(dp + o);
        const f32x4 dvb = *(const f32x4*)(dp + o + 4);
        const int4  svv = *(const int4*)(sp + o);
        const f32x4 Bva = *(const f32x4*)(Bp + o);
        const f32x4 Bvb = *(const f32x4*)(Bp + o + 4);
        const f32x4 Cva = *(const f32x4*)(Cp + o);
        const f32x4 Cvb = *(const f32x4*)(Cp + o + 4);
        bf16 su[8];
        *(int4*)su = svv;
        float e[8], s[8], Cw[8];
        #pragma unroll
        for (int j = 0; j < 4; ++j) {
            e[j]     = __expf(A * dva[j]);
            e[4 + j] = __expf(A * dvb[j]);
            s[j]     = __bfloat162float(su[j]) * Bva[j];
            s[4 + j] = __bfloat162float(su[4 + j]) * Bvb[j];
            Cw[j]     = Cva[j];
            Cw[4 + j] = Cvb[j];
        }
        #pragma unroll
        for (int j = 0; j < 8; ++j) {
            h = e[j] * h + s[j];
            P *= e[j];
            const float cc = row16_sum(h * Cw[j]);
            if (n == 0)
                yp[(size_t)(o + j) * 1024] = __float2bfloat16(cc);
        }
    }
    const size_t so = ((size_t)(b * 8 + c) * 1024 + d) * 16 + n;
    S_end[so] = h;
    P_end[so] = P;
}

// ---------------------------------------------------------------------------
// Chunk-boundary fix
// ---------------------------------------------------------------------------
__global__ __launch_bounds__(256) void fix_k(
    float* __restrict__ S_end, const float* __restrict__ P_end)
{
    const int idx = blockIdx.x * 256 + threadIdx.x;
    const int b = idx >> 14, rem = idx & 16383;
    float* Sb = S_end + (size_t)b * 8 * 16384 + rem;
    const float* Pb = P_end + (size_t)b * 8 * 16384 + rem;
    float h0 = 0.f;
    #pragma unroll
    for (int c = 1; c < 8; ++c) {
        const float s = Sb[(size_t)(c - 1) * 16384];
        const float p = Pb[(size_t)(c - 1) * 16384];
        h0 = s + p * h0;
        Sb[(size_t)(c - 1) * 16384] = h0;
    }
}

// ---------------------------------------------------------------------------
// Chunked scan pass 2: y += C.(P_t*h0).  Chunks 1..7.
// ---------------------------------------------------------------------------
__global__ __launch_bounds__(256) void scan2_k(
    const float* __restrict__ deltaT, const float* __restrict__ bct,
    const float* __restrict__ A_log, const float* __restrict__ h0buf,
    bf16* __restrict__ y)
{
    const int c = blockIdx.y + 1;
    const int b = blockIdx.z;
    const int dl = threadIdx.x >> 4, n = threadIdx.x & 15;
    const int d = blockIdx.x * 16 + dl;
    const float A = -__expf(A_log[d * 16 + n]);
    float q = h0buf[((size_t)(b * 8 + c - 1) * 1024 + d) * 16 + n];
    const int base = b * 1024 + c * 128;
    const float* dp = deltaT + (size_t)d * 4096 + base;
    const float* Cp = bct + (size_t)(16 + n) * 4096 + base;
    bf16* yp = y + (size_t)base * 1024 + d;

    for (int g = 0; g < 16; ++g) {
        const int o = g * 8;
        const f32x4 dva = *(const f32x4*)(dp + o);
        const f32x4 dvb = *(const f32x4*)(dp + o + 4);
        const f32x4 Cva = *(const f32x4*)(Cp + o);
        const f32x4 Cvb = *(const f32x4*)(Cp + o + 4);
        float e[8], Cw[8];
        #pragma unroll
        for (int j = 0; j < 4; ++j) {
            e[j]     = __expf(A * dva[j]);
            e[4 + j] = __expf(A * dvb[j]);
            Cw[j]     = Cva[j];
            Cw[4 + j] = Cvb[j];
        }
        #pragma unroll
        for (int j = 0; j < 8; ++j) {
            q *= e[j];
            const float cc = row16_sum(q * Cw[j]);
            if (n == 0) {
                bf16* p = yp + (size_t)(o + j) * 1024;
                *p = __float2bfloat16(__bfloat162float(*p) + cc);
            }
        }
    }
}

// ---------------------------------------------------------------------------
// gate: y <- (y + u*Dp) * silu(res)
// ---------------------------------------------------------------------------
__global__ __launch_bounds__(256) void gate_k(
    bf16* __restrict__ y, const bf16* __restrict__ uc,
    const bf16* __restrict__ res, const float* __restrict__ Dp)
{
    const int idx = blockIdx.x * 256 + threadIdx.x;
    const int d = idx & 1023;
    const float c = __bfloat162float(y[idx]);
    const float u = __bfloat162float(uc[idx]);
    const float r = __bfloat162float(res[idx]);
    const float gate = r / (1.f + __expf(-r));
    y[idx] = __float2bfloat16((c + u * Dp[d]) * gate);
}

// ---------------------------------------------------------------------------
extern "C" void kernel_launch(void* const* d_in, const int* in_sizes, int n_in,
                              void* d_out, int out_size, void* d_ws, size_t ws_size,
                              hipStream_t stream)
{
    const float* x         = (const float*)d_in[0];
    const float* in_w      = (const float*)d_in[1];
    const float* in_b      = (const float*)d_in[2];
    const float* norm_w    = (const float*)d_in[3];
    const float* inproj_w  = (const float*)d_in[4];
    const float* conv_w    = (const float*)d_in[5];
    const float* conv_b    = (const float*)d_in[6];
    const float* xproj_w   = (const float*)d_in[7];
    const float* dt_w      = (const float*)d_in[8];
    const float* dt_b      = (const float*)d_in[9];
    const float* A_log     = (const float*)d_in[10];
    const float* Dp        = (const float*)d_in[11];
    const float* outproj_w = (const float*)d_in[12];
    const float* normf_w   = (const float*)d_in[13];
    const float* out_w     = (const float*)d_in[14];
    float* out = (float*)d_out;

    char* ws = (char*)d_ws;
    float* h      = (float*)(ws);               //  8388608 B
    bf16*  hn     = (bf16*)(ws + 8388608);      //  4194304 (scan phase: S/P overlay)
    float* S_end  = (float*)(ws + 8388608);     //  2097152 (overlay on hn)
    float* P_end  = (float*)(ws + 10485760);    //  2097152 (overlay on hn)
    bf16*  u_raw  = (bf16*)(ws + 12582912);     //  8388608 (later reused as duT)
    bf16*  res    = (bf16*)(ws + 20971520);     //  8388608
    bf16*  uc     = (bf16*)(ws + 29360128);     //  8388608
    float* xdbl   = (float*)(ws + 37748736);    //  1048576
    float* deltaT = (float*)(ws + 38797312);    // 16777216
    bf16*  yb     = (bf16*)(ws + 55574528);     //  8388608
    bf16*  xb     = (bf16*)(ws + 63963136);     //   655360 (dead after 1st GEMM)
    float* bct    = (float*)(ws + 63963136);    //   524288 (reuses xb region)
    bf16*  w_in   = (bf16*)(ws + 64618496);     //    81920
    bf16*  w_inp  = (bf16*)(ws + 64700416);     // 12582912
    bf16*  w_xp   = (bf16*)(ws + 77283328);     //   786432
    bf16*  w_outp = (bf16*)(ws + 78069760);     //  6291456
    bf16*  w_out  = (bf16*)(ws + 84361216);     //    81920
    bf16*  duT    = u_raw;                      // overlay: u_raw dead after conv

    const int M = 4096;  // B*L tokens

    cvt_k<<<cdiv(4096 * 80, 1024), 256, 0, stream>>>(x, xb, 4096 * 80);
    cvt_k<<<cdiv(512 * 80, 1024), 256, 0, stream>>>(in_w, w_in, 512 * 80);
    cvt_k<<<cdiv(6 * 2048 * 512, 1024), 256, 0, stream>>>(inproj_w, w_inp, 6 * 2048 * 512);
    cvt_k<<<cdiv(6 * 64 * 1024, 1024), 256, 0, stream>>>(xproj_w, w_xp, 6 * 64 * 1024);
    cvt_k<<<cdiv(6 * 512 * 1024, 1024), 256, 0, stream>>>(outproj_w, w_outp, 6 * 512 * 1024);
    cvt_k<<<cdiv(80 * 512, 1024), 256, 0, stream>>>(out_w, w_out, 80 * 512);

    // input projection: h = x @ in_w^T + in_b   [4096,512] K=80
    gemm_bt<1, true><<<dim3(512 / 64, M / 64), 256, 0, stream>>>(
        xb, w_in, in_b, h, nullptr, M, 512, 80);

    for (int i = 0; i < 6; ++i) {
        rmsnorm_k<<<M / 4, 256, 0, stream>>>(h, norm_w + (size_t)i * 512, hn);
        // split projection: u_raw | res = hn @ inproj_w^T   [4096,2048] K=512
        // 128-tile: grid 16x32 = 512 blocks (2/CU) — the regime where it wins
        gemm128_bt<3><<<dim3(2048 / 128, M / 128), 256, 0, stream>>>(
            hn, w_inp + (size_t)i * 2048 * 512, u_raw, res, 2048, 512);
        conv_silu_k<<<(M * 1024) / 256, 256, 0, stream>>>(
            u_raw, conv_w + (size_t)i * 1024 * 4, conv_b + (size_t)i * 1024, uc);
        // xdbl = uc @ xproj_w^T  [4096,64] K=1024, + B/C transposed into bct
        gemm_bt<4, false><<<dim3(1, M / 64), 256, 0, stream>>>(
            uc, w_xp + (size_t)i * 64 * 1024, nullptr, xdbl, bct, M, 64, 1024);
        dtproj_k<<<dim3(M / 16, 4), 256, 0, stream>>>(
            xdbl, uc, dt_w + (size_t)i * 1024 * 32, dt_b + (size_t)i * 1024,
            deltaT, duT);
        scan1_k<<<dim3(64, 8, 4), 256, 0, stream>>>(
            deltaT, duT, bct, A_log + (size_t)i * 1024 * 16, yb, S_end, P_end);
        fix_k<<<65536 / 256, 256, 0, stream>>>(S_end, P_end);
        scan2_k<<<dim3(64, 7, 4), 256, 0, stream>>>(
            deltaT, bct, A_log + (size_t)i * 1024 * 16, S_end, yb);
        gate_k<<<(M * 1024) / 256, 256, 0, stream>>>(
            yb, uc, res, Dp + (size_t)i * 1024);
        // h += yb @ outproj_w^T  [4096,512] K=1024  (64-tile: 512-block grid)
        gemm_bt<2, false><<<dim3(512 / 64, M / 64), 256, 0, stream>>>(
            yb, w_outp + (size_t)i * 512 * 1024, nullptr, h, nullptr, M, 512, 1024);
    }

    rmsnorm_k<<<M / 4, 256, 0, stream>>>(h, normf_w, hn);
    // out = hn @ out_w^T   [4096,80] K=512  (fp32 output)
    gemm_bt<1, false><<<dim3(cdiv(80, 64), M / 64), 256, 0, stream>>>(
        hn, w_out, nullptr, out, nullptr, M, 80, 512);
}